// Round 6
// baseline (3408.942 us; speedup 1.0000x reference)
//
#include <hip/hip_runtime.h>
#include <stdint.h>

// ---------------------------------------------------------------------------
// GenLSTM r6: r3's PROVEN flag protocol, with the allocator fixed.
// 256 WGs x 512 thr (1/CU): WG = (jwg 0..7 gate-slice, grp 0..31 batch-32).
// Changes vs r3 (protocol byte-identical):
//  - amdgpu_waves_per_eu(2,2): VGPR cap 256 -> wreg (148) truly resident.
//  - LDS padded >80KB (oversized ybuf) -> hard 1 WG/CU, no stacking.
//  - noise/dt prefetched to regs BEFORE the GEMM; LDS-staged post-flag.
// Per step: GEMM(37 MFMA) -> cell -> u64 relaxed-agent h stores -> y_partial
// -> B2 (vmcnt drain = release) -> flag -> own-slice to LDS + stage x + y_red
// -> 8-thread flag poll -> B3 -> refill (AGLD u64 pairs) -> B1.
// ---------------------------------------------------------------------------

#define NGRP 32
#define KF_X 5
#define KF_H 32
#define KF_TOT 37
#define MAIN_FRAGS (8 * 8 * KF_TOT)  // jwg * wave * kf = 2368
#define Y_FRAGS 64                   // 2 row-tiles * 32 k-frags
#define TOT_FRAGS (MAIN_FRAGS + Y_FRAGS)
#define HOFF 33554432ull
#define COFF (HOFF + 524288ull)

typedef __attribute__((ext_vector_type(8))) short short8;
typedef __attribute__((ext_vector_type(4))) float f32x4;
typedef __attribute__((ext_vector_type(16))) float f32x16;
typedef __attribute__((ext_vector_type(4))) unsigned int u32x4;
typedef __attribute__((ext_vector_type(2))) unsigned int u32x2;

__device__ __forceinline__ unsigned short f2bf(float x) {
  unsigned int u = __float_as_uint(x);
  u += 0x7FFFu + ((u >> 16) & 1u);
  return (unsigned short)(u >> 16);
}
__device__ __forceinline__ unsigned int pk2(float a, float b) {
  return (unsigned)f2bf(a) | ((unsigned)f2bf(b) << 16);
}
// unit permutation for h k-slots: bijection [0,512) <-> (kz, hi, j)
__device__ __forceinline__ int uperm(int kz, int hi, int j) {
  return 64 * (kz >> 2) + 16 * (kz & 3) + 8 * (j >> 2) + 2 * (j & 3) + hi;
}

__global__ void prep_pack(const float* __restrict__ Wih,
                          const float* __restrict__ Whh,
                          const float* __restrict__ bih,
                          const float* __restrict__ bhh,
                          const float* __restrict__ Wout,
                          const float* __restrict__ bout,
                          unsigned short* __restrict__ pack,
                          int* __restrict__ flags) {
  int tid = blockIdx.x * blockDim.x + threadIdx.x;
  if (blockIdx.x == 0) {
    for (int i = threadIdx.x; i < NGRP * 256; i += blockDim.x) flags[i] = 0;
  }
  int fi = tid >> 6, l = tid & 63;
  if (fi >= TOT_FRAGS) return;
  int r = l & 31, hi = l >> 5;
  unsigned short o[8];
  if (fi < MAIN_FRAGS) {
    int jwg = fi / (8 * KF_TOT);
    int rem = fi % (8 * KF_TOT);
    int w = rem / KF_TOT, kf = rem % KF_TOT;
    int g2 = r & 3, s = r >> 3, hb = (r >> 2) & 1;
    int row = g2 * 512 + jwg * 64 + w * 8 + 2 * s + hb;  // W row (4H space)
    for (int j = 0; j < 8; ++j) {
      float v;
      if (kf < KF_X) {
        int kx = kf * 16 + 8 * hi + j;
        if (kx < 64) {
          v = Wih[row * 129 + 64 + kx];
        } else if (kx == 64) {
          v = Wih[row * 129 + 128];
        } else if (kx == 65) {  // const-1 column: fused bias
          float a = bih[row] + bhh[row];
          for (int q = 0; q < 64; ++q) a += Wih[row * 129 + q] * bout[q];
          v = a;
        } else if (kx == 66) {  // t==0 indicator: cancel Wy@b_out
          float a = 0.f;
          for (int q = 0; q < 64; ++q) a -= Wih[row * 129 + q] * bout[q];
          v = a;
        } else {
          v = 0.f;
        }
      } else {
        int kz = kf - KF_X;
        int U = uperm(kz, hi, j);
        float a = Whh[row * 512 + U];
        for (int q = 0; q < 64; ++q) a += Wih[row * 129 + q] * Wout[q * 512 + U];
        v = a;
      }
      o[j] = f2bf(v);
    }
  } else {
    int fy = fi - MAIN_FRAGS;
    int ry = fy >> 5, kz = fy & 31;
    int row = ry * 32 + r;  // W_out row
    for (int j = 0; j < 8; ++j) {
      int U = uperm(kz, hi, j);
      o[j] = f2bf(Wout[row * 512 + U]);
    }
  }
  unsigned short* dst = pack + (size_t)fi * 512 + l * 8;
  for (int j = 0; j < 8; ++j) dst[j] = o[j];
}

#define AGLD(p) \
  __hip_atomic_load((p), __ATOMIC_RELAXED, __HIP_MEMORY_SCOPE_AGENT)
#define AGST(p, v) \
  __hip_atomic_store((p), (v), __ATOMIC_RELAXED, __HIP_MEMORY_SCOPE_AGENT)

__global__ __launch_bounds__(512)
__attribute__((amdgpu_waves_per_eu(2, 2))) void lstm_main(
    const float* __restrict__ noise, const float* __restrict__ dts,
    const unsigned short* __restrict__ pack, const float* __restrict__ bout,
    unsigned short* __restrict__ hbuf, int* __restrict__ flags,
    float* __restrict__ out) {
  __shared__ __align__(16) unsigned short act[KF_TOT * 512];  // 37 KB
  // ybuf oversized on purpose: total LDS 84.6 KB > 80 KB -> hard 1 WG/CU.
  __shared__ __align__(16) float ybuf[11700];
  const int tid = threadIdx.x;
  const int w = tid >> 6, l = tid & 63;
  const int r = l & 31, hi = l >> 5;
  const int bid = blockIdx.x;
  const int jwg = bid >> 5, grp = bid & 31;
  const int bat = grp * 32 + r;

  // zero LDS h-frags (h_{-1} = 0)
  for (int i = tid; i < (KF_H * 512) / 2; i += 512)
    ((unsigned int*)(act + KF_X * 512))[i] = 0u;

  // register-resident weight slice: 37 frags (148 VGPR), pinned
  short8 wreg[KF_TOT];
  {
    const unsigned short* wl =
        pack + (size_t)((jwg * 8 + w) * KF_TOT) * 512 + l * 8;
#pragma unroll
    for (int kf = 0; kf < KF_TOT; ++kf)
      wreg[kf] = *(const short8*)(wl + (size_t)kf * 512);
#pragma unroll
    for (int kf = 0; kf < KF_TOT; ++kf) asm volatile("" : "+v"(wreg[kf]));
  }

  float c_st[4] = {0.f, 0.f, 0.f, 0.f}, hf[4] = {0.f, 0.f, 0.f, 0.f};
  float4 bo4[4];
  if (jwg < 2 && w == 2) {
#pragma unroll
    for (int s = 0; s < 4; ++s)
      bo4[s] = *(const float4*)(bout + 32 * jwg + 8 * s + 4 * hi);
  }

  auto stage_x0 = [&]() {
    if (w < 4) {
      const float* np = noise + (size_t)bat * 512 * 64 + w * 16 + 8 * hi;
      float4 f0 = *(const float4*)np;
      float4 f1 = *(const float4*)(np + 4);
      u32x4 d;
      d[0] = pk2(f0.x, f0.y);
      d[1] = pk2(f0.z, f0.w);
      d[2] = pk2(f1.x, f1.y);
      d[3] = pk2(f1.z, f1.w);
      *(u32x4*)&act[w * 512 + l * 8] = d;
    } else if (w == 4) {
      u32x4 d = {0u, 0u, 0u, 0u};
      if (hi == 0) {
        float dt = dts[(size_t)bat * 512];
        d[0] = pk2(dt, 1.0f);
        d[1] = pk2(1.0f, 0.0f);  // t==0 indicator
      }
      *(u32x4*)&act[4 * 512 + l * 8] = d;
    }
  };

  auto y_partial = [&]() {  // jwg<2 && w<2: partial over 16 k-frags
    const unsigned short* yl =
        pack + (size_t)(MAIN_FRAGS + jwg * 32 + w * 16) * 512 + l * 8;
    f32x16 ya;
#pragma unroll
    for (int i = 0; i < 16; ++i) ya[i] = 0.f;
    short8 ywr[4];
#pragma unroll
    for (int p = 0; p < 4; ++p) ywr[p] = *(const short8*)(yl + (size_t)p * 512);
#pragma unroll
    for (int q = 0; q < 16; ++q) {
      short8 bv = *(const short8*)&act[(KF_X + w * 16 + q) * 512 + l * 8];
      ya = __builtin_amdgcn_mfma_f32_32x32x16_bf16(ywr[q & 3], bv, ya, 0, 0, 0);
      if (q + 4 < 16)
        ywr[q & 3] = *(const short8*)(yl + (size_t)(q + 4) * 512);
    }
#pragma unroll
    for (int s = 0; s < 4; ++s) {
      f32x4 v = {ya[4 * s], ya[4 * s + 1], ya[4 * s + 2], ya[4 * s + 3]};
      *(f32x4*)&ybuf[(w * 64 + l) * 17 + 4 * s] = v;
    }
  };

  auto y_reduce = [&](int tw) {  // jwg<2 && w==2
#pragma unroll
    for (int s = 0; s < 4; ++s) {
      f32x4 a = *(f32x4*)&ybuf[l * 17 + 4 * s];
      f32x4 b = *(f32x4*)&ybuf[(64 + l) * 17 + 4 * s];
      float4 o;
      o.x = a[0] + b[0] + bo4[s].x;
      o.y = a[1] + b[1] + bo4[s].y;
      o.z = a[2] + b[2] + bo4[s].z;
      o.w = a[3] + b[3] + bo4[s].w;
      *(float4*)(out + ((size_t)bat * 512 + tw) * 64 + 32 * jwg + 8 * s +
                 4 * hi) = o;
    }
  };

  stage_x0();
  __syncthreads();

#pragma unroll 1
  for (int t = 0; t < 512; ++t) {
    // A: prefetch x(t+1) into regs (consumed after the flag store)
    float4 nf0, nf1;
    float dtv = 0.f;
    if (t < 511) {
      if (w < 4) {
        const float* np =
            noise + ((size_t)bat * 512 + t + 1) * 64 + w * 16 + 8 * hi;
        nf0 = *(const float4*)np;
        nf1 = *(const float4*)(np + 4);
      } else if (w == 4 && hi == 0) {
        dtv = dts[(size_t)bat * 512 + t + 1];
      }
    }

    // B: main GEMM: 37 MFMAs, weights from registers, activations from LDS
    f32x16 acc;
#pragma unroll
    for (int i = 0; i < 16; ++i) acc[i] = 0.f;
#pragma unroll
    for (int kf = 0; kf < KF_TOT; ++kf) {
      short8 bv = *(const short8*)&act[kf * 512 + l * 8];
      acc = __builtin_amdgcn_mfma_f32_32x32x16_bf16(wreg[kf], bv, acc, 0, 0, 0);
    }

    // D: in-lane LSTM cell (reg 4s+g -> gate g of unit jwg*64+w*8+2s+hi)
#pragma unroll
    for (int s = 0; s < 4; ++s) {
      float iv = acc[4 * s + 0], fv = acc[4 * s + 1];
      float gv = acc[4 * s + 2], ov = acc[4 * s + 3];
      float ig = 1.f / (1.f + __expf(-iv));
      float fg = 1.f / (1.f + __expf(-fv));
      float e2g = __expf(2.f * gv);
      float gg = 1.f - 2.f / (e2g + 1.f);
      float og = 1.f / (1.f + __expf(-ov));
      float cn = fg * c_st[s] + ig * gg;
      float e2c = __expf(2.f * cn);
      float tc = 1.f - 2.f / (e2c + 1.f);
      c_st[s] = cn;
      hf[s] = og * tc;
    }

    // E: publish h slice — u64 relaxed-agent store, fire & forget
    const int kz_own = 4 * jwg + (w >> 1);
    {
      unsigned long long hv =
          (unsigned long long)pk2(hf[0], hf[1]) |
          ((unsigned long long)pk2(hf[2], hf[3]) << 32);
      unsigned long long* hp = (unsigned long long*)(
          hbuf + ((size_t)(grp * 2 + (t & 1)) * KF_H + kz_own) * 512 + l * 8 +
          4 * (w & 1));
      AGST(hp, hv);
    }

    if (jwg < 2 && w < 2 && t > 0) y_partial();  // y_{t-1} (reads act h)

    __syncthreads();  // B2: drains vmcnt -> h stores at coherence point;
                      // also: all act reads of step t done

    if (tid == 0)
      AGST(&flags[grp * 256 + jwg * 32], t + 1);

    // own slice straight into LDS (skip the LLC round trip for it)
    {
      u32x2 d;
      d[0] = pk2(hf[0], hf[1]);
      d[1] = pk2(hf[2], hf[3]);
      *(u32x2*)&act[(KF_X + kz_own) * 512 + l * 8 + 4 * (w & 1)] = d;
    }

    if (jwg < 2 && w == 2 && t > 0) y_reduce(t - 1);

    // H: stage x(t+1) from prefetched regs
    if (t < 511) {
      if (w < 4) {
        u32x4 d;
        d[0] = pk2(nf0.x, nf0.y);
        d[1] = pk2(nf0.z, nf0.w);
        d[2] = pk2(nf1.x, nf1.y);
        d[3] = pk2(nf1.z, nf1.w);
        *(u32x4*)&act[w * 512 + l * 8] = d;
      } else if (w == 4) {
        u32x4 d = {0u, 0u, 0u, 0u};
        if (hi == 0) d[0] = pk2(dtv, 1.0f);  // indicator = 0 for t+1 >= 1
        *(u32x4*)&act[4 * 512 + l * 8] = d;
      }
    }

    if (tid < 8) {
      while (AGLD(&flags[grp * 256 + tid * 32]) < t + 1)
        __builtin_amdgcn_s_sleep(1);
    }
    __syncthreads();  // B3: all 8 slices published

    // refill other slices: pass p -> frag f=8p+w (wave-uniform skip of own)
    {
      const unsigned long long* src = (const unsigned long long*)(
          hbuf + (size_t)(grp * 2 + (t & 1)) * KF_H * 512);
#pragma unroll
      for (int p = 0; p < 4; ++p) {
        int f = 8 * p + w;
        if ((f >> 2) != jwg) {
          int idx = f * 128 + l * 2;
          unsigned long long q0 = AGLD(src + idx);
          unsigned long long q1 = AGLD(src + idx + 1);
          u32x4 d;
          d[0] = (unsigned)q0;
          d[1] = (unsigned)(q0 >> 32);
          d[2] = (unsigned)q1;
          d[3] = (unsigned)(q1 >> 32);
          *(u32x4*)&act[(KF_X + f) * 512 + l * 8] = d;
        }
      }
    }
    __syncthreads();  // B1: act ready for next step
  }

  // epilogue: y_511 + final h,c
  if (jwg < 2 && w < 2) y_partial();
  __syncthreads();
  if (jwg < 2 && w == 2) y_reduce(511);
#pragma unroll
  for (int s = 0; s < 4; ++s) {
    int U = 64 * jwg + 8 * w + 2 * s + hi;
    out[HOFF + (size_t)bat * 512 + U] = hf[s];
    out[COFF + (size_t)bat * 512 + U] = c_st[s];
  }
}

extern "C" void kernel_launch(void* const* d_in, const int* in_sizes, int n_in,
                              void* d_out, int out_size, void* d_ws,
                              size_t ws_size, hipStream_t stream) {
  (void)in_sizes;
  (void)n_in;
  (void)out_size;
  (void)ws_size;
  const float* noise = (const float*)d_in[0];
  const float* dts = (const float*)d_in[1];
  const float* Wih = (const float*)d_in[2];
  const float* Whh = (const float*)d_in[3];
  const float* bih = (const float*)d_in[4];
  const float* bhh = (const float*)d_in[5];
  const float* Wout = (const float*)d_in[6];
  const float* bout = (const float*)d_in[7];

  unsigned short* pack = (unsigned short*)d_ws;               // 2.49 MB
  unsigned short* hbuf = pack + (size_t)TOT_FRAGS * 512;      // 2.00 MB
  int* flags = (int*)(hbuf + (size_t)NGRP * 2 * KF_H * 512);  // 32 KB

  prep_pack<<<(TOT_FRAGS * 64 + 255) / 256, 256, 0, stream>>>(
      Wih, Whh, bih, bhh, Wout, bout, pack, flags);
  lstm_main<<<256, 512, 0, stream>>>(noise, dts, pack, bout, hbuf, flags,
                                     (float*)d_out);
}

// Round 7
// 2639.068 us; speedup vs baseline: 1.2917x; 1.2917x over previous
//
#include <hip/hip_runtime.h>
#include <stdint.h>

// ---------------------------------------------------------------------------
// GenLSTM r7: 4-wave WGs, 1 wave/SIMD, 512-VGPR budget -> weights RESIDENT.
// 256 WGs x 256 thr: WG = (jwg 0..7 gate-slice, grp 0..31 batch-32).
// Each wave owns TWO row-tiles (old slices 2w, 2w+1): wA/wB = 296 VGPR,
// both tiles share each B-fragment (one ds_read feeds two MFMAs).
// Protocol = r3's proven flag scheme, unchanged. Refill batched (1 RT).
// Publish: full 16B lane slot at kz=4*jwg+w (tile e in shorts 4e..4e+3),
// verified vs uperm: u = 64*jwg + 16*w + 8*e + 2*s + hi.
// ---------------------------------------------------------------------------

#define NGRP 32
#define KF_X 5
#define KF_H 32
#define KF_TOT 37
#define MAIN_FRAGS (8 * 8 * KF_TOT)  // jwg * slice * kf = 2368
#define Y_FRAGS 64                   // 2 row-tiles * 32 k-frags
#define TOT_FRAGS (MAIN_FRAGS + Y_FRAGS)
#define HOFF 33554432ull
#define COFF (HOFF + 524288ull)

typedef __attribute__((ext_vector_type(8))) short short8;
typedef __attribute__((ext_vector_type(4))) float f32x4;
typedef __attribute__((ext_vector_type(16))) float f32x16;
typedef __attribute__((ext_vector_type(4))) unsigned int u32x4;

__device__ __forceinline__ unsigned short f2bf(float x) {
  unsigned int u = __float_as_uint(x);
  u += 0x7FFFu + ((u >> 16) & 1u);
  return (unsigned short)(u >> 16);
}
__device__ __forceinline__ unsigned int pk2(float a, float b) {
  return (unsigned)f2bf(a) | ((unsigned)f2bf(b) << 16);
}
// unit permutation for h k-slots: bijection [0,512) <-> (kz, hi, j)
__device__ __forceinline__ int uperm(int kz, int hi, int j) {
  return 64 * (kz >> 2) + 16 * (kz & 3) + 8 * (j >> 2) + 2 * (j & 3) + hi;
}

__global__ void prep_pack(const float* __restrict__ Wih,
                          const float* __restrict__ Whh,
                          const float* __restrict__ bih,
                          const float* __restrict__ bhh,
                          const float* __restrict__ Wout,
                          const float* __restrict__ bout,
                          unsigned short* __restrict__ pack,
                          int* __restrict__ flags) {
  int tid = blockIdx.x * blockDim.x + threadIdx.x;
  if (blockIdx.x == 0) {
    for (int i = threadIdx.x; i < NGRP * 256; i += blockDim.x) flags[i] = 0;
  }
  int fi = tid >> 6, l = tid & 63;
  if (fi >= TOT_FRAGS) return;
  int r = l & 31, hi = l >> 5;
  unsigned short o[8];
  if (fi < MAIN_FRAGS) {
    int jwg = fi / (8 * KF_TOT);
    int rem = fi % (8 * KF_TOT);
    int w = rem / KF_TOT, kf = rem % KF_TOT;
    int g2 = r & 3, s = r >> 3, hb = (r >> 2) & 1;
    int row = g2 * 512 + jwg * 64 + w * 8 + 2 * s + hb;  // W row (4H space)
    for (int j = 0; j < 8; ++j) {
      float v;
      if (kf < KF_X) {
        int kx = kf * 16 + 8 * hi + j;
        if (kx < 64) {
          v = Wih[row * 129 + 64 + kx];
        } else if (kx == 64) {
          v = Wih[row * 129 + 128];
        } else if (kx == 65) {  // const-1 column: fused bias
          float a = bih[row] + bhh[row];
          for (int q = 0; q < 64; ++q) a += Wih[row * 129 + q] * bout[q];
          v = a;
        } else if (kx == 66) {  // t==0 indicator: cancel Wy@b_out
          float a = 0.f;
          for (int q = 0; q < 64; ++q) a -= Wih[row * 129 + q] * bout[q];
          v = a;
        } else {
          v = 0.f;
        }
      } else {
        int kz = kf - KF_X;
        int U = uperm(kz, hi, j);
        float a = Whh[row * 512 + U];
        for (int q = 0; q < 64; ++q) a += Wih[row * 129 + q] * Wout[q * 512 + U];
        v = a;
      }
      o[j] = f2bf(v);
    }
  } else {
    int fy = fi - MAIN_FRAGS;
    int ry = fy >> 5, kz = fy & 31;
    int row = ry * 32 + r;  // W_out row
    for (int j = 0; j < 8; ++j) {
      int U = uperm(kz, hi, j);
      o[j] = f2bf(Wout[row * 512 + U]);
    }
  }
  unsigned short* dst = pack + (size_t)fi * 512 + l * 8;
  for (int j = 0; j < 8; ++j) dst[j] = o[j];
}

#define AGLD(p) \
  __hip_atomic_load((p), __ATOMIC_RELAXED, __HIP_MEMORY_SCOPE_AGENT)
#define AGST(p, v) \
  __hip_atomic_store((p), (v), __ATOMIC_RELAXED, __HIP_MEMORY_SCOPE_AGENT)

__global__ __launch_bounds__(256)
__attribute__((amdgpu_waves_per_eu(1, 1))) void lstm_main(
    const float* __restrict__ noise, const float* __restrict__ dts,
    const unsigned short* __restrict__ pack, const float* __restrict__ bout,
    unsigned short* __restrict__ hbuf, int* __restrict__ flags,
    float* __restrict__ out) {
  __shared__ __align__(16) unsigned short act[KF_TOT * 512];  // 37 KB
  __shared__ __align__(16) float ybuf[4 * 64 * 17];           // 17.4 KB padded
  const int tid = threadIdx.x;
  const int w = tid >> 6, l = tid & 63;
  const int r = l & 31, hi = l >> 5;
  const int bid = blockIdx.x;
  const int jwg = bid >> 5, grp = bid & 31;
  const int bat = grp * 32 + r;

  // zero LDS h-frags (h_{-1} = 0)
  for (int i = tid; i < (KF_H * 512) / 2; i += 256)
    ((unsigned int*)(act + KF_X * 512))[i] = 0u;

  // register-resident weight slices 2w and 2w+1: 74 frags = 296 VGPR
  short8 wA[KF_TOT], wB[KF_TOT];
  {
    const unsigned short* wl =
        pack + (size_t)((jwg * 8 + 2 * w) * KF_TOT) * 512 + l * 8;
#pragma unroll
    for (int kf = 0; kf < KF_TOT; ++kf) {
      wA[kf] = *(const short8*)(wl + (size_t)kf * 512);
      wB[kf] = *(const short8*)(wl + (size_t)(KF_TOT + kf) * 512);
    }
#pragma unroll
    for (int kf = 0; kf < KF_TOT; ++kf) {
      asm volatile("" : "+v"(wA[kf]));
      asm volatile("" : "+v"(wB[kf]));
    }
  }

  float c0[4] = {0.f, 0.f, 0.f, 0.f}, c1[4] = {0.f, 0.f, 0.f, 0.f};
  float h0[4] = {0.f, 0.f, 0.f, 0.f}, h1[4] = {0.f, 0.f, 0.f, 0.f};
  float4 bo = {0.f, 0.f, 0.f, 0.f};
  if (jwg < 2) bo = *(const float4*)(bout + 32 * jwg + 8 * w + 4 * hi);

  auto cell = [&](const f32x16& a, float* cs, float* hs) {
#pragma unroll
    for (int s = 0; s < 4; ++s) {
      float iv = a[4 * s + 0], fv = a[4 * s + 1];
      float gv = a[4 * s + 2], ov = a[4 * s + 3];
      float ig = 1.f / (1.f + __expf(-iv));
      float fg = 1.f / (1.f + __expf(-fv));
      float e2g = __expf(2.f * gv);
      float gg = 1.f - 2.f / (e2g + 1.f);
      float og = 1.f / (1.f + __expf(-ov));
      float cn = fg * cs[s] + ig * gg;
      float e2c = __expf(2.f * cn);
      float tc = 1.f - 2.f / (e2c + 1.f);
      cs[s] = cn;
      hs[s] = og * tc;
    }
  };

  auto y_partial = [&]() {  // jwg<2, all 4 waves: kf slice w*8..w*8+7
    const unsigned short* yl =
        pack + (size_t)(MAIN_FRAGS + jwg * 32 + w * 8) * 512 + l * 8;
    f32x16 ya;
#pragma unroll
    for (int i = 0; i < 16; ++i) ya[i] = 0.f;
    short8 ywr[4];
#pragma unroll
    for (int p = 0; p < 4; ++p) ywr[p] = *(const short8*)(yl + (size_t)p * 512);
#pragma unroll
    for (int q = 0; q < 8; ++q) {
      short8 bv = *(const short8*)&act[(KF_X + w * 8 + q) * 512 + l * 8];
      ya = __builtin_amdgcn_mfma_f32_32x32x16_bf16(ywr[q & 3], bv, ya, 0, 0, 0);
      if (q + 4 < 8)
        ywr[q & 3] = *(const short8*)(yl + (size_t)(q + 4) * 512);
    }
#pragma unroll
    for (int s = 0; s < 4; ++s) {
      f32x4 v = {ya[4 * s], ya[4 * s + 1], ya[4 * s + 2], ya[4 * s + 3]};
      *(f32x4*)&ybuf[(w * 64 + l) * 17 + 4 * s] = v;
    }
  };

  auto y_sum = [&](int tw) {  // jwg<2, all 4 waves: q-slice 4w..4w+3
    f32x4 s0 = *(f32x4*)&ybuf[(0 * 64 + l) * 17 + 4 * w];
    f32x4 s1 = *(f32x4*)&ybuf[(1 * 64 + l) * 17 + 4 * w];
    f32x4 s2 = *(f32x4*)&ybuf[(2 * 64 + l) * 17 + 4 * w];
    f32x4 s3 = *(f32x4*)&ybuf[(3 * 64 + l) * 17 + 4 * w];
    float4 o;
    o.x = s0[0] + s1[0] + s2[0] + s3[0] + bo.x;
    o.y = s0[1] + s1[1] + s2[1] + s3[1] + bo.y;
    o.z = s0[2] + s1[2] + s2[2] + s3[2] + bo.z;
    o.w = s0[3] + s1[3] + s2[3] + s3[3] + bo.w;
    *(float4*)(out + ((size_t)bat * 512 + tw) * 64 + 32 * jwg + 8 * w +
               4 * hi) = o;
  };

  // prologue: stage x(0) (t0 indicator = 1)
  {
    const float* np = noise + (size_t)bat * 512 * 64 + w * 16 + 8 * hi;
    float4 f0 = *(const float4*)np;
    float4 f1 = *(const float4*)(np + 4);
    u32x4 d;
    d[0] = pk2(f0.x, f0.y);
    d[1] = pk2(f0.z, f0.w);
    d[2] = pk2(f1.x, f1.y);
    d[3] = pk2(f1.z, f1.w);
    *(u32x4*)&act[w * 512 + l * 8] = d;
    if (w == 0) {
      u32x4 d4 = {0u, 0u, 0u, 0u};
      if (hi == 0) {
        float dt = dts[(size_t)bat * 512];
        d4[0] = pk2(dt, 1.0f);
        d4[1] = pk2(1.0f, 0.0f);  // t==0 indicator
      }
      *(u32x4*)&act[4 * 512 + l * 8] = d4;
    }
  }
  __syncthreads();

  const int kz_own = 4 * jwg + w;

#pragma unroll 1
  for (int t = 0; t < 512; ++t) {
    // A: prefetch x(t+1) into regs (free at 512-VGPR budget)
    float4 nf0, nf1;
    float dtv = 0.f;
    if (t < 511) {
      const float* np =
          noise + ((size_t)bat * 512 + t + 1) * 64 + w * 16 + 8 * hi;
      nf0 = *(const float4*)np;
      nf1 = *(const float4*)(np + 4);
      if (w == 0 && hi == 0) dtv = dts[(size_t)bat * 512 + t + 1];
    }

    // B: GEMM — 37 shared B-frags feed 2 MFMAs each (tiles 2w, 2w+1)
    f32x16 a0, a1;
#pragma unroll
    for (int i = 0; i < 16; ++i) {
      a0[i] = 0.f;
      a1[i] = 0.f;
    }
#pragma unroll
    for (int kf = 0; kf < KF_TOT; ++kf) {
      short8 bv = *(const short8*)&act[kf * 512 + l * 8];
      a0 = __builtin_amdgcn_mfma_f32_32x32x16_bf16(wA[kf], bv, a0, 0, 0, 0);
      a1 = __builtin_amdgcn_mfma_f32_32x32x16_bf16(wB[kf], bv, a1, 0, 0, 0);
    }

    // D: in-lane LSTM cells (gate = q&3, unit = jwg*64+(2w+e)*8+2s+hi)
    cell(a0, c0, h0);
    cell(a1, c1, h1);

    // E: publish full 16B lane slot at kz_own (fire & forget)
    unsigned int p0 = pk2(h0[0], h0[1]), p1 = pk2(h0[2], h0[3]);
    unsigned int p2 = pk2(h1[0], h1[1]), p3 = pk2(h1[2], h1[3]);
    {
      unsigned long long* hp = (unsigned long long*)(
          hbuf + ((size_t)(grp * 2 + (t & 1)) * KF_H + kz_own) * 512 + l * 8);
      AGST(hp, (unsigned long long)p0 | ((unsigned long long)p1 << 32));
      AGST(hp + 1, (unsigned long long)p2 | ((unsigned long long)p3 << 32));
    }

    if (jwg < 2 && t > 0) y_partial();  // y_{t-1} from h_{t-1} in act

    __syncthreads();  // B2: vmcnt drained -> h stores at coherence point

    if (tid == 0) AGST(&flags[grp * 256 + jwg * 32], t + 1);

    if (jwg < 2 && t > 0) y_sum(t - 1);

    // H: stage x(t+1) from prefetched regs
    if (t < 511) {
      u32x4 d;
      d[0] = pk2(nf0.x, nf0.y);
      d[1] = pk2(nf0.z, nf0.w);
      d[2] = pk2(nf1.x, nf1.y);
      d[3] = pk2(nf1.z, nf1.w);
      *(u32x4*)&act[w * 512 + l * 8] = d;
      if (w == 0) {
        u32x4 d4 = {0u, 0u, 0u, 0u};
        if (hi == 0) d4[0] = pk2(dtv, 1.0f);  // indicator = 0 for t+1
        *(u32x4*)&act[4 * 512 + l * 8] = d4;
      }
    }

    if (tid < 8) {
      while (AGLD(&flags[grp * 256 + tid * 32]) < t + 1)
        __builtin_amdgcn_s_sleep(1);
    }
    __syncthreads();  // B3: all 8 slices published

    // refill ALL 32 frags (incl. own — bit-identical), batched: 1 RT
    {
      const unsigned long long* src = (const unsigned long long*)(
          hbuf + (size_t)(grp * 2 + (t & 1)) * KF_H * 512);
      unsigned long long q[16];
#pragma unroll
      for (int k = 0; k < 8; ++k) {
        int idx = (4 * k + w) * 128 + l * 2;
        q[2 * k] = AGLD(src + idx);
        q[2 * k + 1] = AGLD(src + idx + 1);
      }
#pragma unroll
      for (int k = 0; k < 8; ++k) {
        u32x4 d;
        d[0] = (unsigned)q[2 * k];
        d[1] = (unsigned)(q[2 * k] >> 32);
        d[2] = (unsigned)q[2 * k + 1];
        d[3] = (unsigned)(q[2 * k + 1] >> 32);
        *(u32x4*)&act[(KF_X + 4 * k + w) * 512 + l * 8] = d;
      }
    }
    __syncthreads();  // B1: act ready for next step
  }

  // epilogue: y_511 + final h,c
  if (jwg < 2) y_partial();
  __syncthreads();
  if (jwg < 2) y_sum(511);
#pragma unroll
  for (int s = 0; s < 4; ++s) {
    int U0 = jwg * 64 + (2 * w + 0) * 8 + 2 * s + hi;
    int U1 = jwg * 64 + (2 * w + 1) * 8 + 2 * s + hi;
    out[HOFF + (size_t)bat * 512 + U0] = h0[s];
    out[COFF + (size_t)bat * 512 + U0] = c0[s];
    out[HOFF + (size_t)bat * 512 + U1] = h1[s];
    out[COFF + (size_t)bat * 512 + U1] = c1[s];
  }
}

extern "C" void kernel_launch(void* const* d_in, const int* in_sizes, int n_in,
                              void* d_out, int out_size, void* d_ws,
                              size_t ws_size, hipStream_t stream) {
  (void)in_sizes;
  (void)n_in;
  (void)out_size;
  (void)ws_size;
  const float* noise = (const float*)d_in[0];
  const float* dts = (const float*)d_in[1];
  const float* Wih = (const float*)d_in[2];
  const float* Whh = (const float*)d_in[3];
  const float* bih = (const float*)d_in[4];
  const float* bhh = (const float*)d_in[5];
  const float* Wout = (const float*)d_in[6];
  const float* bout = (const float*)d_in[7];

  unsigned short* pack = (unsigned short*)d_ws;               // 2.49 MB
  unsigned short* hbuf = pack + (size_t)TOT_FRAGS * 512;      // 2.00 MB
  int* flags = (int*)(hbuf + (size_t)NGRP * 2 * KF_H * 512);  // 32 KB

  prep_pack<<<(TOT_FRAGS * 64 + 255) / 256, 256, 0, stream>>>(
      Wih, Whh, bih, bhh, Wout, bout, pack, flags);
  lstm_main<<<256, 256, 0, stream>>>(noise, dts, pack, bout, hbuf, flags,
                                     (float*)d_out);
}